// Round 2
// baseline (344.248 us; speedup 1.0000x reference)
//
#include <hip/hip_runtime.h>
#include <hip/hip_bf16.h>

// SeqAttention: out = (Q K^T) V  ==  Q (K^T V)   [softmax + key_pe are dead code]
// B=8, M=2048, L=2048, H=1024. Inputs/outputs fp32; internal compute bf16 MFMA
// (threshold is 8x bf16 floor -> bf16 compute is sanctioned).
//
// Stages:
//   0. Qb  = bf16(Q)                          [B,M,H]
//   1. Kt  = bf16(K^T), Vt = bf16(V^T)        [B,H,L]  (L-contraction contiguous)
//   2. GEMM1: W[b][j][h] = sum_l Vt[j][l]*Kt[h][l]  (= (K^T V)^T, bf16)
//   3. GEMM2: O[b][m][j] = sum_h Qb[m][h]*W[j][h]   (fp32 out)
// Both GEMMs are NT (A row-major, Bt row-major, contiguous K) — m97 structure:
// 128x128 tile, BK=32, global_load_lds width=16, mfma_f32_16x16x32_bf16.

typedef __bf16 bf16x8 __attribute__((ext_vector_type(8)));
typedef float f32x4 __attribute__((ext_vector_type(4)));
typedef unsigned short u16_t;

#define GLD_LDS16(g, l)                                                        \
  __builtin_amdgcn_global_load_lds(                                            \
      (const __attribute__((address_space(1))) void*)(g),                      \
      (__attribute__((address_space(3))) void*)(l), 16, 0, 0)

static __device__ inline u16_t f2b(float x) {
  __hip_bfloat16 h = __float2bfloat16(x);
  u16_t u;
  __builtin_memcpy(&u, &h, 2);
  return u;
}

// ---------------------------------------------------------------------------
// Elementwise fp32 -> bf16 (8 elements/thread).
__global__ __launch_bounds__(256) void cvt_f32_bf16(
    const float* __restrict__ in, u16_t* __restrict__ out, size_t n8) {
  const size_t i = (size_t)blockIdx.x * 256 + threadIdx.x;
  if (i >= n8) return;
  const float4 a = *(const float4*)(in + i * 8);
  const float4 b = *(const float4*)(in + i * 8 + 4);
  u16_t v[8] = {f2b(a.x), f2b(a.y), f2b(a.z), f2b(a.w),
                f2b(b.x), f2b(b.y), f2b(b.z), f2b(b.w)};
  *(uint4*)(out + i * 8) = *(const uint4*)v;
}

// ---------------------------------------------------------------------------
// fp32 [L,H] -> bf16 [H,L] per batch (blockIdx.z). 64x64 tiles via LDS.
__global__ __launch_bounds__(256) void transpose_cvt(
    const float* __restrict__ in, u16_t* __restrict__ out, int L, int Hd) {
  __shared__ u16_t tile[64 * 65];
  in  += (size_t)blockIdx.z * (size_t)L * Hd;
  out += (size_t)blockIdx.z * (size_t)L * Hd;
  const int h0 = blockIdx.x * 64;
  const int l0 = blockIdx.y * 64;

  // Load: 64(l) x 64(h) fp32; thread handles 4 float4s.
  const int c4 = (threadIdx.x & 15) * 4;  // h-offset
  const int r0 = threadIdx.x >> 4;        // 0..15
#pragma unroll
  for (int it = 0; it < 4; ++it) {
    const int r = r0 + 16 * it;  // l-offset
    const float4 f = *(const float4*)(in + (size_t)(l0 + r) * Hd + h0 + c4);
    tile[(c4 + 0) * 65 + r] = f2b(f.x);
    tile[(c4 + 1) * 65 + r] = f2b(f.y);
    tile[(c4 + 2) * 65 + r] = f2b(f.z);
    tile[(c4 + 3) * 65 + r] = f2b(f.w);
  }
  __syncthreads();

  // Store: 64(h) rows x 64(l) bf16; thread handles 2 uint4s.
  const int c8 = (threadIdx.x & 7) * 8;  // l-offset
  const int rr = threadIdx.x >> 3;       // 0..31
#pragma unroll
  for (int it = 0; it < 2; ++it) {
    const int r = rr + 32 * it;  // h-offset
    u16_t p[8];
#pragma unroll
    for (int u = 0; u < 8; ++u) p[u] = tile[r * 65 + c8 + u];
    *(uint4*)(out + (size_t)(h0 + r) * L + l0 + c8) = *(const uint4*)p;
  }
}

// ---------------------------------------------------------------------------
static __device__ inline void store_c(float* p, float v) { *p = v; }
static __device__ inline void store_c(u16_t* p, float v) { *p = f2b(v); }

// C[m][n] = sum_k A[m][k] * Bt[n][k], per batch (blockIdx.z).
// A: [M,K] bf16 row-major, Bt: [N,K] bf16 row-major, C: [M,N] OutT.
template <typename OutT>
__global__ __launch_bounds__(256) void gemm_bt_128(
    const u16_t* __restrict__ A, const u16_t* __restrict__ Bt,
    OutT* __restrict__ C, int M, int N, int K, long sA, long sB, long sC) {
  __shared__ __align__(16) u16_t As[128 * 32];
  __shared__ __align__(16) u16_t Bs[128 * 32];

  A  += (size_t)blockIdx.z * (size_t)sA;
  Bt += (size_t)blockIdx.z * (size_t)sB;
  C  += (size_t)blockIdx.z * (size_t)sC;

  const int tid = threadIdx.x;
  const int m0 = blockIdx.y * 128;
  const int n0 = blockIdx.x * 128;

  const int lane = tid & 63;
  const int w  = tid >> 6;
  const int wm = w & 1;   // wave row half
  const int wn = w >> 1;  // wave col half
  const int s  = lane & 15;
  const int q  = lane >> 4;

  // Staging: idx in [0,512) = 128 rows x 4 sixteen-byte chunks.
  const int i0 = tid, i1 = tid + 256;
  const u16_t* gA0 = A  + (size_t)(m0 + (i0 >> 2)) * K + (i0 & 3) * 8;
  const u16_t* gA1 = A  + (size_t)(m0 + (i1 >> 2)) * K + (i1 & 3) * 8;
  const u16_t* gB0 = Bt + (size_t)(n0 + (i0 >> 2)) * K + (i0 & 3) * 8;
  const u16_t* gB1 = Bt + (size_t)(n0 + (i1 >> 2)) * K + (i1 & 3) * 8;
  u16_t* lA0 = As + i0 * 8;
  u16_t* lA1 = As + i1 * 8;
  u16_t* lB0 = Bs + i0 * 8;
  u16_t* lB1 = Bs + i1 * 8;

  f32x4 acc[4][4];
#pragma unroll
  for (int r = 0; r < 4; ++r)
#pragma unroll
    for (int c = 0; c < 4; ++c) acc[r][c] = (f32x4){0.f, 0.f, 0.f, 0.f};

  for (int k0 = 0; k0 < K; k0 += 32) {
    GLD_LDS16(gA0 + k0, lA0);
    GLD_LDS16(gA1 + k0, lA1);
    GLD_LDS16(gB0 + k0, lB0);
    GLD_LDS16(gB1 + k0, lB1);
    __syncthreads();

    bf16x8 af[4], bfr[4];
#pragma unroll
    for (int r = 0; r < 4; ++r)
      af[r] = *(const bf16x8*)(As + (64 * wm + 16 * r + s) * 32 + q * 8);
#pragma unroll
    for (int c = 0; c < 4; ++c)
      bfr[c] = *(const bf16x8*)(Bs + (64 * wn + 16 * c + s) * 32 + q * 8);
#pragma unroll
    for (int r = 0; r < 4; ++r)
#pragma unroll
      for (int c = 0; c < 4; ++c)
        acc[r][c] = __builtin_amdgcn_mfma_f32_16x16x32_bf16(af[r], bfr[c],
                                                            acc[r][c], 0, 0, 0);
    __syncthreads();
  }

  // C/D layout (m89-verified): col = lane&15, row = (lane>>4)*4 + reg
#pragma unroll
  for (int r = 0; r < 4; ++r) {
#pragma unroll
    for (int c = 0; c < 4; ++c) {
      const int col = n0 + 64 * wn + 16 * c + s;
#pragma unroll
      for (int e = 0; e < 4; ++e) {
        const int row = m0 + 64 * wm + 16 * r + q * 4 + e;
        store_c(&C[(size_t)row * N + col], acc[r][c][e]);
      }
    }
  }
}

// ---------------------------------------------------------------------------
extern "C" void kernel_launch(void* const* d_in, const int* in_sizes, int n_in,
                              void* d_out, int out_size, void* d_ws, size_t ws_size,
                              hipStream_t stream) {
  const int B = 8, M = 2048, L = 2048, H = 1024;

  const float* q = (const float*)d_in[0];  // [B,M,H] fp32
  const float* k = (const float*)d_in[1];  // [B,L,H] fp32
  const float* v = (const float*)d_in[2];  // [B,L,H] fp32
  // d_in[3] = key_pe (dead code), d_in[4] = hidden_size (unused)

  const size_t nKt = (size_t)B * H * L;  // 16.78M
  const size_t nQ  = (size_t)B * M * H;  // 16.78M
  const size_t nW  = (size_t)B * H * H;  // 8.39M
  const size_t need = (2 * nKt + nQ + nW) * sizeof(u16_t);  // 112 MiB
  if (ws_size < need) return;  // early-out -> absmax would be exactly 8128

  u16_t* Kt = (u16_t*)d_ws;  // [B,H,L] bf16
  u16_t* Vt = Kt + nKt;      // [B,H,L] bf16
  u16_t* Qb = Vt + nKt;      // [B,M,H] bf16
  u16_t* W  = Qb + nQ;       // [B,H,H] bf16: W[j][h] = (K^T V)[h][j]

  dim3 tb(256);

  cvt_f32_bf16<<<dim3((unsigned)(nQ / 8 / 256)), tb, 0, stream>>>(q, Qb, nQ / 8);

  dim3 tg(H / 64, L / 64, B);
  transpose_cvt<<<tg, tb, 0, stream>>>(k, Kt, L, H);
  transpose_cvt<<<tg, tb, 0, stream>>>(v, Vt, L, H);

  // GEMM1: W[j][h] = sum_l Vt[j][l] * Kt[h][l]   (M=N=1024, K=2048)
  dim3 g1(H / 128, H / 128, B);
  gemm_bt_128<u16_t><<<g1, tb, 0, stream>>>(Vt, Kt, W, H, H, L,
                                            (long)H * L, (long)H * L, (long)H * H);

  // GEMM2: O[m][j] = sum_h Qb[m][h] * W[j][h]    (M=2048, N=1024, K=1024)
  dim3 g2(H / 128, M / 128, B);
  gemm_bt_128<float><<<g2, tb, 0, stream>>>(Qb, W, (float*)d_out, M, H, H,
                                            (long)M * H, (long)H * H, (long)M * H);
}

// Round 3
// 315.090 us; speedup vs baseline: 1.0925x; 1.0925x over previous
//
#include <hip/hip_runtime.h>
#include <hip/hip_bf16.h>

// SeqAttention: out = (Q K^T) V  ==  Q (K^T V)   [softmax + key_pe are dead code]
// B=8, M=2048, L=2048, H=1024. fp32 in/out; bf16 MFMA internal.
//
// Stages:
//   0. Qb  = bf16(Q)                          [B,M,H]
//   1. Kt  = bf16(K^T), Vt = bf16(V^T)        [B,H,L]
//   2. GEMM1: W[b][j][h] = sum_l Vt[j][l]*Kt[h][l]  (bf16 out)
//   3. GEMM2: O[b][m][j] = sum_h Qb[m][h]*W[j][h]   (fp32 out)
//
// R3 changes vs R2 (which measured MfmaUtil 19%, 4.19M LDS conflicts, 140MB fetch):
//  - BK=64 + XOR-swizzled LDS (slot = chunk ^ (row&7)): fragment ds_read_b128
//    spreads over all 32 banks (2-way = free), staging stays contiguous-by-lane
//    as global_load_lds requires (swizzle applied to the GLOBAL source chunk).
//  - XCD-aware 1D grid: batch = blockIdx.x & 7 -> each XCD's L2 caches one
//    batch's B operand instead of all XCDs fetching all batches.

typedef __bf16 bf16x8 __attribute__((ext_vector_type(8)));
typedef float f32x4 __attribute__((ext_vector_type(4)));
typedef unsigned short u16_t;

#define GLD_LDS16(g, l)                                                        \
  __builtin_amdgcn_global_load_lds(                                            \
      (const __attribute__((address_space(1))) void*)(g),                      \
      (__attribute__((address_space(3))) void*)(l), 16, 0, 0)

static __device__ inline u16_t f2b(float x) {
  __hip_bfloat16 h = __float2bfloat16(x);
  u16_t u;
  __builtin_memcpy(&u, &h, 2);
  return u;
}

// ---------------------------------------------------------------------------
// Elementwise fp32 -> bf16 (8 elements/thread).
__global__ __launch_bounds__(256) void cvt_f32_bf16(
    const float* __restrict__ in, u16_t* __restrict__ out, size_t n8) {
  const size_t i = (size_t)blockIdx.x * 256 + threadIdx.x;
  if (i >= n8) return;
  const float4 a = *(const float4*)(in + i * 8);
  const float4 b = *(const float4*)(in + i * 8 + 4);
  u16_t v[8] = {f2b(a.x), f2b(a.y), f2b(a.z), f2b(a.w),
                f2b(b.x), f2b(b.y), f2b(b.z), f2b(b.w)};
  *(uint4*)(out + i * 8) = *(const uint4*)v;
}

// ---------------------------------------------------------------------------
// fp32 [L,H] -> bf16 [H,L] per batch (blockIdx.z). 64x64 tiles via LDS.
__global__ __launch_bounds__(256) void transpose_cvt(
    const float* __restrict__ in, u16_t* __restrict__ out, int L, int Hd) {
  __shared__ u16_t tile[64 * 65];
  in  += (size_t)blockIdx.z * (size_t)L * Hd;
  out += (size_t)blockIdx.z * (size_t)L * Hd;
  const int h0 = blockIdx.x * 64;
  const int l0 = blockIdx.y * 64;

  const int c4 = (threadIdx.x & 15) * 4;  // h-offset
  const int r0 = threadIdx.x >> 4;        // 0..15
#pragma unroll
  for (int it = 0; it < 4; ++it) {
    const int r = r0 + 16 * it;  // l-offset
    const float4 f = *(const float4*)(in + (size_t)(l0 + r) * Hd + h0 + c4);
    tile[(c4 + 0) * 65 + r] = f2b(f.x);
    tile[(c4 + 1) * 65 + r] = f2b(f.y);
    tile[(c4 + 2) * 65 + r] = f2b(f.z);
    tile[(c4 + 3) * 65 + r] = f2b(f.w);
  }
  __syncthreads();

  const int c8 = (threadIdx.x & 7) * 8;  // l-offset
  const int rr = threadIdx.x >> 3;       // 0..31
#pragma unroll
  for (int it = 0; it < 2; ++it) {
    const int r = rr + 32 * it;  // h-offset
    u16_t p[8];
#pragma unroll
    for (int u = 0; u < 8; ++u) p[u] = tile[r * 65 + c8 + u];
    *(uint4*)(out + (size_t)(h0 + r) * L + l0 + c8) = *(const uint4*)p;
  }
}

// ---------------------------------------------------------------------------
static __device__ inline void store_c(float* p, float v) { *p = v; }
static __device__ inline void store_c(u16_t* p, float v) { *p = f2b(v); }

// C[m][n] = sum_k A[m][k] * Bt[n][k].
// 1D grid: blockIdx.x = (t << 3) | batch; t -> (tm = t>>3, tn = t&7).
// N must be 1024 (8 n-tiles); M multiple of 128; K multiple of 64.
// LDS layout: As[row][slot*8..], slot = chunk ^ (row&7)  (BK=64 -> 8 chunks/row).
template <typename OutT>
__global__ __launch_bounds__(256) void gemm_bt_128(
    const u16_t* __restrict__ A, const u16_t* __restrict__ Bt,
    OutT* __restrict__ C, int M, int N, int K, long sA, long sB, long sC) {
  __shared__ __align__(16) u16_t As[128 * 64];
  __shared__ __align__(16) u16_t Bs[128 * 64];

  const int batch = blockIdx.x & 7;
  const int t = blockIdx.x >> 3;
  const int m0 = (t >> 3) * 128;
  const int n0 = (t & 7) * 128;

  A  += (size_t)batch * (size_t)sA;
  Bt += (size_t)batch * (size_t)sB;
  C  += (size_t)batch * (size_t)sC;

  const int tid = threadIdx.x;
  const int lane = tid & 63;
  const int w  = tid >> 6;
  const int wm = w & 1;   // wave row half
  const int wn = w >> 1;  // wave col half
  const int s  = lane & 15;
  const int q  = lane >> 4;

  // Staging: i in [0,1024) = 128 rows x 8 sixteen-byte chunks. Thread handles
  // i = tid + 256*j, j=0..3. LDS slot = i&7; global chunk = slot ^ (row&7).
  const u16_t* gA[4];
  const u16_t* gB[4];
  u16_t* lA[4];
  u16_t* lB[4];
#pragma unroll
  for (int j = 0; j < 4; ++j) {
    const int i = tid + 256 * j;
    const int row = i >> 3;
    const int gchunk = (i & 7) ^ (row & 7);
    gA[j] = A  + (size_t)(m0 + row) * K + gchunk * 8;
    gB[j] = Bt + (size_t)(n0 + row) * K + gchunk * 8;
    lA[j] = As + i * 8;
    lB[j] = Bs + i * 8;
  }

  f32x4 acc[4][4];
#pragma unroll
  for (int r = 0; r < 4; ++r)
#pragma unroll
    for (int c = 0; c < 4; ++c) acc[r][c] = (f32x4){0.f, 0.f, 0.f, 0.f};

  // Fragment LDS offsets (elements). Row of A-frag r: 64*wm+16*r+s; its &7 == s&7.
  const int s7 = s & 7;

  for (int k0 = 0; k0 < K; k0 += 64) {
#pragma unroll
    for (int j = 0; j < 4; ++j) {
      GLD_LDS16(gA[j] + k0, lA[j]);
      GLD_LDS16(gB[j] + k0, lB[j]);
    }
    __syncthreads();

#pragma unroll
    for (int kk = 0; kk < 2; ++kk) {
      const int slot = (kk * 4 + q) ^ s7;  // swizzled 16B chunk within row
      bf16x8 af[4], bfr[4];
#pragma unroll
      for (int r = 0; r < 4; ++r)
        af[r] = *(const bf16x8*)(As + (64 * wm + 16 * r + s) * 64 + slot * 8);
#pragma unroll
      for (int c = 0; c < 4; ++c)
        bfr[c] = *(const bf16x8*)(Bs + (64 * wn + 16 * c + s) * 64 + slot * 8);
#pragma unroll
      for (int r = 0; r < 4; ++r)
#pragma unroll
        for (int c = 0; c < 4; ++c)
          acc[r][c] = __builtin_amdgcn_mfma_f32_16x16x32_bf16(af[r], bfr[c],
                                                              acc[r][c], 0, 0, 0);
    }
    __syncthreads();
  }

  // C/D layout (m89-verified): col = lane&15, row = (lane>>4)*4 + reg
#pragma unroll
  for (int r = 0; r < 4; ++r) {
#pragma unroll
    for (int c = 0; c < 4; ++c) {
      const int col = n0 + 64 * wn + 16 * c + s;
#pragma unroll
      for (int e = 0; e < 4; ++e) {
        const int row = m0 + 64 * wm + 16 * r + q * 4 + e;
        store_c(&C[(size_t)row * N + col], acc[r][c][e]);
      }
    }
  }
}

// ---------------------------------------------------------------------------
extern "C" void kernel_launch(void* const* d_in, const int* in_sizes, int n_in,
                              void* d_out, int out_size, void* d_ws, size_t ws_size,
                              hipStream_t stream) {
  const int B = 8, M = 2048, L = 2048, H = 1024;

  const float* q = (const float*)d_in[0];  // [B,M,H] fp32
  const float* k = (const float*)d_in[1];  // [B,L,H] fp32
  const float* v = (const float*)d_in[2];  // [B,L,H] fp32
  // d_in[3] = key_pe (dead code), d_in[4] = hidden_size (unused)

  const size_t nKt = (size_t)B * H * L;
  const size_t nQ  = (size_t)B * M * H;
  const size_t nW  = (size_t)B * H * H;
  const size_t need = (2 * nKt + nQ + nW) * sizeof(u16_t);  // 112 MiB
  if (ws_size < need) return;

  u16_t* Kt = (u16_t*)d_ws;  // [B,H,L] bf16
  u16_t* Vt = Kt + nKt;      // [B,H,L] bf16
  u16_t* Qb = Vt + nKt;      // [B,M,H] bf16
  u16_t* W  = Qb + nQ;       // [B,H,H] bf16: W[j][h] = (K^T V)[h][j]

  dim3 tb(256);

  cvt_f32_bf16<<<dim3((unsigned)(nQ / 8 / 256)), tb, 0, stream>>>(q, Qb, nQ / 8);

  dim3 tg(H / 64, L / 64, B);
  transpose_cvt<<<tg, tb, 0, stream>>>(k, Kt, L, H);
  transpose_cvt<<<tg, tb, 0, stream>>>(v, Vt, L, H);

  // GEMM1: W[j][h] = sum_l Vt[j][l] * Kt[h][l]   (M=N=1024, K=2048)
  gemm_bt_128<u16_t><<<dim3(B * (H / 128) * (H / 128)), tb, 0, stream>>>(
      Vt, Kt, W, H, H, L, (long)H * L, (long)H * L, (long)H * H);

  // GEMM2: O[m][j] = sum_h Qb[m][h] * W[j][h]    (M=2048, N=1024, K=1024)
  gemm_bt_128<float><<<dim3(B * (M / 128) * (H / 128)), tb, 0, stream>>>(
      Qb, W, (float*)d_out, M, H, H, (long)M * H, (long)H * H, (long)M * H);
}